// Round 5
// baseline (90696.667 us; speedup 1.0000x reference)
//
#include <hip/hip_runtime.h>

// GRU bidirectional 2-layer + classifier for MI355X (gfx950).
// Reference GRU variant: hcand = tanh(h_in + (r ⊙ h_prev) @ Uh^T)  (reset
// BEFORE matmul — Python precedence: rt * h @ Uh.T == (rt*h) @ Uh.T).
// Scan: 128 WGs = 16 batch x 8 output-parts, weights in VGPRs, TWO flag-sync
// rounds per step (publish g = r⊙h_prev, then publish h), fwd+bwd chains
// batched per WG. xproj scratch lives in d_out's logits area (dead by
// classifier time). Overwrite safety of the parity double-buffers relies on
// stamp-chaining: a producer can only reach the overwriting phase after all
// consumers provably finished reading the previous-parity data.

#define T_STEPS 1000
#define NB      16
#define DH      512
#define ROWS    (T_STEPS*NB)   // 16000
#define DIN     440
#define DINP    448
#define NCLS    2000
#define NCLSP   2048

typedef _Float16 f16;
typedef _Float16 f16x2 __attribute__((ext_vector_type(2)));
typedef _Float16 f16x8 __attribute__((ext_vector_type(8)));
typedef float    f32x4 __attribute__((ext_vector_type(4)));
typedef unsigned int   u32;
typedef unsigned short u16;

__device__ __forceinline__ float fdot2f(u32 a, u32 b, float c) {
#if __has_builtin(__builtin_amdgcn_fdot2)
  return __builtin_amdgcn_fdot2(__builtin_bit_cast(f16x2, a),
                                __builtin_bit_cast(f16x2, b), c, false);
#else
  f16x2 av = __builtin_bit_cast(f16x2, a), bv = __builtin_bit_cast(f16x2, b);
  return c + (float)av[0]*(float)bv[0] + (float)av[1]*(float)bv[1];
#endif
}

__device__ __forceinline__ float sigm_(float x) {
  x = fminf(fmaxf(x, -30.f), 30.f);
  float e = __expf(-x);
  return __builtin_amdgcn_rcpf(1.f + e);
}
__device__ __forceinline__ float tanh_(float x) {
  float x2 = fminf(fmaxf(2.f*x, -60.f), 60.f);
  float e = __expf(x2);
  return (e - 1.f) * __builtin_amdgcn_rcpf(e + 1.f);
}

// ---------------- prep kernels ----------------

__global__ __launch_bounds__(256) void cvt_pad_k(const float* __restrict__ src,
    u16* __restrict__ dst, int drows, int srows, int skc, int dkc)
{
  int idx = blockIdx.x*256 + threadIdx.x;
  int total = drows*dkc;
  if (idx >= total) return;
  int r = idx / dkc, k = idx - r*dkc;
  float v = (r < srows && k < skc) ? src[(size_t)r*skc + k] : 0.f;
  dst[idx] = __builtin_bit_cast(u16, (_Float16)v);
}

__global__ __launch_bounds__(256) void pack_pairs_k(const float* __restrict__ U,
    u32* __restrict__ dst)
{
  int idx = blockIdx.x*256 + threadIdx.x;  // 512*256
  if (idx >= 512*256) return;
  int i = idx >> 8, p = idx & 255;
  f16x2 v;
  v[0] = (_Float16)U[(size_t)i*512 + 2*p];
  v[1] = (_Float16)U[(size_t)i*512 + 2*p + 1];
  dst[idx] = __builtin_bit_cast(u32, v);
}

__global__ __launch_bounds__(256) void cat3_k(const float* __restrict__ a,
    const float* __restrict__ b, const float* __restrict__ c, float* __restrict__ d)
{
  int i = blockIdx.x*256 + threadIdx.x;
  if (i < 512) d[i] = a[i];
  else if (i < 1024) d[i] = b[i-512];
  else if (i < 1536) d[i] = c[i-1024];
}

__global__ __launch_bounds__(256) void scan_init_k(u32* __restrict__ h_ex32,
    u32* __restrict__ g_ex32, u32* __restrict__ h_st, u32* __restrict__ g_st)
{
  int i = blockIdx.x*256 + threadIdx.x;   // grid 160*256 = 40960
  if (i < 16384) h_ex32[i] = 0u;   // 16 pb x 2 chain x 2 par x 256 u32
  if (i < 16384) g_ex32[i] = 0u;
  if (i < 4096)  { h_st[i] = 0u; g_st[i] = 0u; }
}

// ---------------- GEMM (f16 MFMA, A:[M][K], B:[N][K] row-major = B^T) ----------

template<bool OUT_HALF, bool NGUARD>
__global__ __launch_bounds__(256) void gemm_f16_k(
    const u16* __restrict__ A, const u16* __restrict__ B,
    const float* __restrict__ bias, void* __restrict__ Cout,
    int K, int ntiles, int ldc, int nreal)
{
  __shared__ __align__(16) u16 As[128*40];   // row stride 40 f16 = 80B
  __shared__ __align__(16) u16 Bs[128*40];
  const int blk = blockIdx.x;
  const int bm = blk / ntiles, bn = blk % ntiles;
  const int t = threadIdx.x;
  const int l = t & 63, w = t >> 6;
  const int wr = w >> 1, wc = w & 1;
  const int srow = t >> 1, kh = t & 1;
  const int lr = l & 15, kb = l >> 4;

  f32x4 acc[4][4];
  #pragma unroll
  for (int m = 0; m < 4; ++m)
    #pragma unroll
    for (int n = 0; n < 4; ++n) acc[m][n] = (f32x4)0.0f;

  const u16* pa = A + (size_t)(bm*128 + srow)*K + kh*16;
  const u16* pb = B + (size_t)(bn*128 + srow)*K + kh*16;
  const int ktiles = K >> 5;
  for (int kt = 0; kt < ktiles; ++kt) {
    uint4 va0 = *(const uint4*)(pa);
    uint4 va1 = *(const uint4*)(pa + 8);
    uint4 vb0 = *(const uint4*)(pb);
    uint4 vb1 = *(const uint4*)(pb + 8);
    pa += 32; pb += 32;
    __syncthreads();
    *(uint4*)(As + srow*40 + kh*16)     = va0;
    *(uint4*)(As + srow*40 + kh*16 + 8) = va1;
    *(uint4*)(Bs + srow*40 + kh*16)     = vb0;
    *(uint4*)(Bs + srow*40 + kh*16 + 8) = vb1;
    __syncthreads();
    f16x8 af[4], bf[4];
    #pragma unroll
    for (int m = 0; m < 4; ++m)
      af[m] = *(const f16x8*)(As + (wr*64 + m*16 + lr)*40 + kb*8);
    #pragma unroll
    for (int n = 0; n < 4; ++n)
      bf[n] = *(const f16x8*)(Bs + (wc*64 + n*16 + lr)*40 + kb*8);
    #pragma unroll
    for (int m = 0; m < 4; ++m)
      #pragma unroll
      for (int n = 0; n < 4; ++n)
        acc[m][n] = __builtin_amdgcn_mfma_f32_16x16x32_f16(af[m], bf[n], acc[m][n], 0, 0, 0);
  }

  #pragma unroll
  for (int n = 0; n < 4; ++n) {
    int col = bn*128 + wc*64 + n*16 + lr;
    bool ok = (!NGUARD) || (col < nreal);
    float bv = ok ? bias[col] : 0.f;
    #pragma unroll
    for (int m = 0; m < 4; ++m) {
      #pragma unroll
      for (int r = 0; r < 4; ++r) {
        int row = bm*128 + wr*64 + m*16 + kb*4 + r;
        float v = acc[m][n][r] + bv;
        if (ok) {
          if (OUT_HALF)
            ((u16*)Cout)[(size_t)row*ldc + col] = __builtin_bit_cast(u16, (_Float16)v);
          else
            ((float*)Cout)[(size_t)row*ldc + col] = v;
        }
      }
    }
  }
}

// ---------------- GRU scan ----------------
// WG (pb, part): outputs [part*64, part*64+64) for BOTH chains (fwd, bwd).
// Thread: iout = t0>>3, jg = t0&7 (64-wide j-slice). Weights 96 u32 in VGPRs.
// Step t: A) wait h(t) -> az,ar -> z,r -> publish g = r*h_prev
//         B) wait g(t+1) -> ah -> h_new -> publish h.
// Fast-poll first 8 iters (stamp usually in flight), then s_sleep backoff.
#define WAIT_GE(addr, need) do { u32 _s = 0; \
    while (!dead && __hip_atomic_load((addr), __ATOMIC_RELAXED, \
                                      __HIP_MEMORY_SCOPE_AGENT) < (u32)(need)) { \
      ++_s; if (_s > 8u) __builtin_amdgcn_s_sleep(1); \
      if (_s > 300000u) dead = 1; } } while (0)

__global__ __launch_bounds__(512, 2) void gru_scan_k(
    const u16* __restrict__ xproj,   // [16000][1536] f16, gates z,r,h
    const u32* __restrict__ Upack,   // [3][512][256] f16x2 pairs (z,r,h)
    u16* __restrict__ outh,          // [16000][1024] f16
    u16* __restrict__ h_ex,          // [16][2][2][512]
    u16* __restrict__ g_ex,          // [16][2][2][512]
    u32* __restrict__ h_st,          // [16][2][8][16]
    u32* __restrict__ g_st)          // [16][2][8][16]
{
  __shared__ volatile int dead;
  const int bid  = blockIdx.x;
  const int part = bid >> 4;         // bid = part*16 + pb -> parts of a pb share XCD
  const int pb   = bid & 15;
  const int t0   = threadIdx.x;
  const int iout = t0 >> 3;
  const int jg   = t0 & 7;
  const int ig   = part*64 + iout;

  if (t0 == 0) dead = 0;

  u32 wz[32], wr_[32], wh[32];
  {
    const uint4* pz = (const uint4*)(Upack + ((size_t)(0*512 + ig)*256 + jg*32));
    const uint4* pr = (const uint4*)(Upack + ((size_t)(1*512 + ig)*256 + jg*32));
    const uint4* ph = (const uint4*)(Upack + ((size_t)(2*512 + ig)*256 + jg*32));
    #pragma unroll
    for (int k = 0; k < 8; ++k) {
      uint4 vz = pz[k]; wz[4*k]=vz.x;  wz[4*k+1]=vz.y;  wz[4*k+2]=vz.z;  wz[4*k+3]=vz.w;
      uint4 vr = pr[k]; wr_[4*k]=vr.x; wr_[4*k+1]=vr.y; wr_[4*k+2]=vr.z; wr_[4*k+3]=vr.w;
      uint4 vh = ph[k]; wh[4*k]=vh.x;  wh[4*k+1]=vh.y;  wh[4*k+2]=vh.z;  wh[4*k+3]=vh.w;
    }
  }
  __syncthreads();

  u32* hst0 = h_st + (pb*2 + 0)*128;
  u32* hst1 = h_st + (pb*2 + 1)*128;
  u32* gst0 = g_st + (pb*2 + 0)*128;
  u32* gst1 = g_st + (pb*2 + 1)*128;
  u16* hex0 = h_ex + (pb*2 + 0)*1024;   // [2 par][512]
  u16* hex1 = h_ex + (pb*2 + 1)*1024;
  u16* gex0 = g_ex + (pb*2 + 0)*1024;
  u16* gex1 = g_ex + (pb*2 + 1)*1024;

  float hprev0 = 0.f, hprev1 = 0.f;

  for (int t = 0; t < T_STEPS; ++t) {
    const int par  = t & 1;
    const int row0 = t*NB + pb;
    const int row1 = (T_STEPS-1 - t)*NB + pb;

    // x-projection loads (h-independent) — issue before the spin so their
    // latency hides under the wait.
    const u16* xp0 = xproj + (size_t)row0*1536 + ig;
    const u16* xp1 = xproj + (size_t)row1*1536 + ig;
    float xz0 = (float)__builtin_bit_cast(_Float16, xp0[0]);
    float xr0 = (float)__builtin_bit_cast(_Float16, xp0[512]);
    float xh0 = (float)__builtin_bit_cast(_Float16, xp0[1024]);
    float xz1 = (float)__builtin_bit_cast(_Float16, xp1[0]);
    float xr1 = (float)__builtin_bit_cast(_Float16, xp1[512]);
    float xh1 = (float)__builtin_bit_cast(_Float16, xp1[1024]);

    // ---- phase A: z/r matvecs on h(t) ----
    WAIT_GE(hst0 + jg*16, t);
    WAIT_GE(hst1 + jg*16, t);
    __builtin_amdgcn_fence(__ATOMIC_ACQUIRE, "agent");

    u32 h0a[32], h1a[32];
    {
      const uint4* h0p = (const uint4*)(hex0 + par*512 + jg*64);
      const uint4* h1p = (const uint4*)(hex1 + par*512 + jg*64);
      #pragma unroll
      for (int k = 0; k < 8; ++k) {
        uint4 v = h0p[k]; h0a[4*k]=v.x; h0a[4*k+1]=v.y; h0a[4*k+2]=v.z; h0a[4*k+3]=v.w;
      }
      #pragma unroll
      for (int k = 0; k < 8; ++k) {
        uint4 v = h1p[k]; h1a[4*k]=v.x; h1a[4*k+1]=v.y; h1a[4*k+2]=v.z; h1a[4*k+3]=v.w;
      }
    }
    float az0=0.f, ar0=0.f, az1=0.f, ar1=0.f;
    #pragma unroll
    for (int j = 0; j < 32; ++j) {
      az0 = fdot2f(wz[j],  h0a[j], az0);
      ar0 = fdot2f(wr_[j], h0a[j], ar0);
      az1 = fdot2f(wz[j],  h1a[j], az1);
      ar1 = fdot2f(wr_[j], h1a[j], ar1);
    }
    #pragma unroll
    for (int m = 1; m < 8; m <<= 1) {
      az0 += __shfl_xor(az0, m); ar0 += __shfl_xor(ar0, m);
      az1 += __shfl_xor(az1, m); ar1 += __shfl_xor(ar1, m);
    }
    float z0 = sigm_(xz0 + az0);
    float r0 = sigm_(xr0 + ar0);
    float g0 = r0 * hprev0;
    float z1 = sigm_(xz1 + az1);
    float r1 = sigm_(xr1 + ar1);
    float g1 = r1 * hprev1;

    if (jg == 0) {
      gex0[par*512 + ig] = __builtin_bit_cast(u16, (_Float16)g0);
      gex1[par*512 + ig] = __builtin_bit_cast(u16, (_Float16)g1);
    }
    __builtin_amdgcn_fence(__ATOMIC_RELEASE, "agent");
    __syncthreads();
    if (t0 == 0) {
      __hip_atomic_store(gst0 + part*16, (u32)(t+1), __ATOMIC_RELEASE, __HIP_MEMORY_SCOPE_AGENT);
      __hip_atomic_store(gst1 + part*16, (u32)(t+1), __ATOMIC_RELEASE, __HIP_MEMORY_SCOPE_AGENT);
    }

    // ---- phase B: Uh matvec on g, state update ----
    WAIT_GE(gst0 + jg*16, t+1);
    WAIT_GE(gst1 + jg*16, t+1);
    __builtin_amdgcn_fence(__ATOMIC_ACQUIRE, "agent");

    u32 g0a[32], g1a[32];
    {
      const uint4* g0p = (const uint4*)(gex0 + par*512 + jg*64);
      const uint4* g1p = (const uint4*)(gex1 + par*512 + jg*64);
      #pragma unroll
      for (int k = 0; k < 8; ++k) {
        uint4 v = g0p[k]; g0a[4*k]=v.x; g0a[4*k+1]=v.y; g0a[4*k+2]=v.z; g0a[4*k+3]=v.w;
      }
      #pragma unroll
      for (int k = 0; k < 8; ++k) {
        uint4 v = g1p[k]; g1a[4*k]=v.x; g1a[4*k+1]=v.y; g1a[4*k+2]=v.z; g1a[4*k+3]=v.w;
      }
    }
    float ah0 = 0.f, ah1 = 0.f;
    #pragma unroll
    for (int j = 0; j < 32; ++j) {
      ah0 = fdot2f(wh[j], g0a[j], ah0);
      ah1 = fdot2f(wh[j], g1a[j], ah1);
    }
    #pragma unroll
    for (int m = 1; m < 8; m <<= 1) {
      ah0 += __shfl_xor(ah0, m); ah1 += __shfl_xor(ah1, m);
    }
    float c0  = tanh_(xh0 + ah0);
    float hn0 = z0*hprev0 + (1.f - z0)*c0;
    float c1  = tanh_(xh1 + ah1);
    float hn1 = z1*hprev1 + (1.f - z1)*c1;
    hprev0 = hn0; hprev1 = hn1;

    if (jg == 0) {
      u16 hb0 = __builtin_bit_cast(u16, (_Float16)hn0);
      u16 hb1 = __builtin_bit_cast(u16, (_Float16)hn1);
      hex0[(par^1)*512 + ig] = hb0;
      hex1[(par^1)*512 + ig] = hb1;
      outh[(size_t)row0*1024 + ig]       = hb0;  // fwd -> cols [0,512)
      outh[(size_t)row1*1024 + 512 + ig] = hb1;  // bwd -> cols [512,1024)
    }
    __builtin_amdgcn_fence(__ATOMIC_RELEASE, "agent");
    __syncthreads();
    if (t0 == 0) {
      __hip_atomic_store(hst0 + part*16, (u32)(t+1), __ATOMIC_RELEASE, __HIP_MEMORY_SCOPE_AGENT);
      __hip_atomic_store(hst1 + part*16, (u32)(t+1), __ATOMIC_RELEASE, __HIP_MEMORY_SCOPE_AGENT);
    }
  }
}

// ---------------- fused log_softmax + NLL + argmax-err (per row) ----------------

__global__ __launch_bounds__(256) void softmax_nll_k(float* __restrict__ dout,
    const int* __restrict__ lab, float2* __restrict__ part)
{
  __shared__ float sred[8];
  __shared__ int   sredi[4];
  const int row = blockIdx.x;
  float* p = dout + 2 + (size_t)row*NCLS;
  const int t = threadIdx.x;

  float v[8];
  float m = -1e30f; int mi = 0;
  #pragma unroll
  for (int j = 0; j < 8; ++j) {
    int c = t + 256*j;
    float x = (c < NCLS) ? p[c] : -1e30f;
    v[j] = x;
    if (x > m) { m = x; mi = c; }
  }
  #pragma unroll
  for (int off = 1; off < 64; off <<= 1) {
    float om = __shfl_xor(m, off); int oi = __shfl_xor(mi, off);
    if (om > m || (om == m && oi < mi)) { m = om; mi = oi; }
  }
  const int w = t >> 6;
  if ((t & 63) == 0) { sred[w] = m; sredi[w] = mi; }
  __syncthreads();
  if (t == 0) {
    #pragma unroll
    for (int k = 1; k < 4; ++k) {
      float om = sred[k]; int oi = sredi[k];
      if (om > m || (om == m && oi < mi)) { m = om; mi = oi; }
    }
    sred[4] = m; sredi[0] = mi;
  }
  __syncthreads();
  const float gmax = sred[4];
  const int   gidx = sredi[0];

  float s = 0.f;
  #pragma unroll
  for (int j = 0; j < 8; ++j) {
    int c = t + 256*j;
    if (c < NCLS) s += __expf(v[j] - gmax);
  }
  #pragma unroll
  for (int off = 1; off < 64; off <<= 1) s += __shfl_xor(s, off);
  if ((t & 63) == 0) sred[w] = s;
  __syncthreads();
  if (t == 0) sred[5] = gmax + __logf(sred[0] + sred[1] + sred[2] + sred[3]);
  __syncthreads();
  const float lse = sred[5];

  #pragma unroll
  for (int j = 0; j < 8; ++j) {
    int c = t + 256*j;
    if (c < NCLS) p[c] = v[j] - lse;
  }
  __syncthreads();
  if (t == 0) {
    int lb = lab[row];
    float nll = -p[lb];
    float ef = (gidx != lb) ? 1.f : 0.f;
    part[row] = make_float2(nll, ef);
  }
}

__global__ __launch_bounds__(1024) void finred_k(const float2* __restrict__ part,
                                                 float* __restrict__ out)
{
  __shared__ float s0[16], s1[16];
  float a = 0.f, e = 0.f;
  for (int i = threadIdx.x; i < ROWS; i += 1024) {
    float2 v = part[i]; a += v.x; e += v.y;
  }
  #pragma unroll
  for (int off = 1; off < 64; off <<= 1) { a += __shfl_xor(a, off); e += __shfl_xor(e, off); }
  if ((threadIdx.x & 63) == 0) { s0[threadIdx.x >> 6] = a; s1[threadIdx.x >> 6] = e; }
  __syncthreads();
  if (threadIdx.x == 0) {
    float ta = 0.f, te = 0.f;
    #pragma unroll
    for (int k = 0; k < 16; ++k) { ta += s0[k]; te += s1[k]; }
    out[0] = ta * (1.f/16000.f);
    out[1] = te * (1.f/16000.f);
  }
}

// ---------------- launch ----------------

extern "C" void kernel_launch(void* const* d_in, const int* in_sizes, int n_in,
                              void* d_out, int out_size, void* d_ws, size_t ws_size,
                              hipStream_t stream)
{
  const float* x     = (const float*)d_in[0];
  const int*   lab   = (const int*)  d_in[1];
  const float* w0_zx = (const float*)d_in[3];
  const float* b0_zx = (const float*)d_in[4];
  const float* w0_hx = (const float*)d_in[5];
  const float* b0_hx = (const float*)d_in[6];
  const float* w0_rx = (const float*)d_in[7];
  const float* b0_rx = (const float*)d_in[8];
  const float* u0_zh = (const float*)d_in[9];
  const float* u0_hh = (const float*)d_in[10];
  const float* u0_rh = (const float*)d_in[11];
  const float* w1_zx = (const float*)d_in[12];
  const float* b1_zx = (const float*)d_in[13];
  const float* w1_hx = (const float*)d_in[14];
  const float* b1_hx = (const float*)d_in[15];
  const float* w1_rx = (const float*)d_in[16];
  const float* b1_rx = (const float*)d_in[17];
  const float* u1_zh = (const float*)d_in[18];
  const float* u1_hh = (const float*)d_in[19];
  const float* u1_rh = (const float*)d_in[20];
  const float* fco_w = (const float*)d_in[21];
  const float* fco_b = (const float*)d_in[22];

  char* ws = (char*)d_ws;
  u16*   xf    = (u16*)  (ws + 0);            // [16000][448] f16
  u16*   w0c   = (u16*)  (ws + 14336000);     // [1536][448]
  float* b0c   = (float*)(ws + 15712256);     // [1536]
  u32*   u0p   = (u32*)  (ws + 15718400);     // [3][512][256]
  u16*   w1c   = (u16*)  (ws + 17291264);     // [1536][1024]
  float* b1c   = (float*)(ws + 20436992);
  u32*   u1p   = (u32*)  (ws + 20443136);
  u16*   fcoc  = (u16*)  (ws + 22016000);     // [2048][1024]
  u16*   x1    = (u16*)  (ws + 26210304);     // [16000][1024] f16
  float2* part = (float2*)(ws + 58978304);    // [16000]
  u16*   h_ex  = (u16*)  (ws + 59106304);     // [16][2][2][512]
  u16*   g_ex  = (u16*)  (ws + 59171840);     // [16][2][2][512]
  u32*   h_st  = (u32*)  (ws + 59237376);     // [16][2][8][16]
  u32*   g_st  = (u32*)  (ws + 59253760);     // [16][2][8][16]
  float* out   = (float*)d_out;
  u16*   xproj = (u16*)  (out + 2);           // [16000][1536] f16 (scratch in
                                              //  logits area; dead before
                                              //  classifier overwrites it)

  // prep: f32 -> f16 (+padding), gate order z,r,h; biases concatenated
  cvt_pad_k<<<28000,256,0,stream>>>(x, xf, ROWS, ROWS, DIN, DINP);
  cvt_pad_k<<<896,256,0,stream>>>(w0_zx, w0c,          512,512, DIN, DINP);
  cvt_pad_k<<<896,256,0,stream>>>(w0_rx, w0c+512*448,  512,512, DIN, DINP);
  cvt_pad_k<<<896,256,0,stream>>>(w0_hx, w0c+1024*448, 512,512, DIN, DINP);
  cat3_k<<<6,256,0,stream>>>(b0_zx, b0_rx, b0_hx, b0c);
  pack_pairs_k<<<512,256,0,stream>>>(u0_zh, u0p);
  pack_pairs_k<<<512,256,0,stream>>>(u0_rh, u0p + 131072);
  pack_pairs_k<<<512,256,0,stream>>>(u0_hh, u0p + 262144);
  cvt_pad_k<<<2048,256,0,stream>>>(w1_zx, w1c,            512,512, 1024,1024);
  cvt_pad_k<<<2048,256,0,stream>>>(w1_rx, w1c+512*1024,   512,512, 1024,1024);
  cvt_pad_k<<<2048,256,0,stream>>>(w1_hx, w1c+1024*1024,  512,512, 1024,1024);
  cat3_k<<<6,256,0,stream>>>(b1_zx, b1_rx, b1_hx, b1c);
  pack_pairs_k<<<512,256,0,stream>>>(u1_zh, u1p);
  pack_pairs_k<<<512,256,0,stream>>>(u1_rh, u1p + 131072);
  pack_pairs_k<<<512,256,0,stream>>>(u1_hh, u1p + 262144);
  cvt_pad_k<<<8192,256,0,stream>>>(fco_w, fcoc, NCLSP, NCLS, 1024, 1024);

  // pipeline
  gemm_f16_k<true,false><<<125*12,256,0,stream>>>(xf,  w0c, b0c, xproj, DINP, 12, 1536, 1536);
  scan_init_k<<<160,256,0,stream>>>((u32*)h_ex, (u32*)g_ex, h_st, g_st);
  gru_scan_k<<<128,512,0,stream>>>(xproj, u0p, x1, h_ex, g_ex, h_st, g_st);
  gemm_f16_k<true,false><<<125*12,256,0,stream>>>(x1,  w1c, b1c, xproj, 1024, 12, 1536, 1536);
  scan_init_k<<<160,256,0,stream>>>((u32*)h_ex, (u32*)g_ex, h_st, g_st);
  gru_scan_k<<<128,512,0,stream>>>(xproj, u1p, x1, h_ex, g_ex, h_st, g_st);
  gemm_f16_k<false,true><<<125*16,256,0,stream>>>(x1, fcoc, fco_b, out + 2, 1024, 16, NCLS, NCLS);

  softmax_nll_k<<<ROWS,256,0,stream>>>(out, lab, part);
  finred_k<<<1,1024,0,stream>>>(part, out);
}

// Round 7
// 9563.832 us; speedup vs baseline: 9.4833x; 9.4833x over previous
//
#include <hip/hip_runtime.h>

// GRU bidirectional 2-layer + classifier for MI355X (gfx950).
// Reference GRU variant: hcand = tanh(h_in + (r ⊙ h_prev) @ Uh^T).
// Scan: 128 WGs = 16 batch x 8 output-parts, weights in VGPRs.
// Cross-WG exchange is FENCE-FREE: each shared element is a tagged word
// (step_tag<<16)|f16, moved with relaxed agent-scope atomics (sc1 to the
// coherence point; no buffer_inv/wbl2 L2 maintenance — r5's fences cost
// ~32us/round and 200+MB of L2 writeback traffic). 512 threads poll
// disjoint u64 pairs into LDS, one barrier, compute. Overwrite safety of
// the parity double-buffers follows from tag causality: a producer reaches
// the overwriting store only after observing stamps that postdate every
// consumer's checked read of the previous-parity value.

#define T_STEPS 1000
#define NB      16
#define DH      512
#define ROWS    (T_STEPS*NB)   // 16000
#define DIN     440
#define DINP    448
#define NCLS    2000
#define NCLSP   2048
#define SPIN_CAP 20000u

typedef _Float16 f16;
typedef _Float16 f16x2 __attribute__((ext_vector_type(2)));
typedef _Float16 f16x8 __attribute__((ext_vector_type(8)));
typedef float    f32x4 __attribute__((ext_vector_type(4)));
typedef unsigned int   u32;
typedef unsigned short u16;
typedef unsigned long long u64;

__device__ __forceinline__ float fdot2f(u32 a, u32 b, float c) {
#if __has_builtin(__builtin_amdgcn_fdot2)
  return __builtin_amdgcn_fdot2(__builtin_bit_cast(f16x2, a),
                                __builtin_bit_cast(f16x2, b), c, false);
#else
  f16x2 av = __builtin_bit_cast(f16x2, a), bv = __builtin_bit_cast(f16x2, b);
  return c + (float)av[0]*(float)bv[0] + (float)av[1]*(float)bv[1];
#endif
}

__device__ __forceinline__ float sigm_(float x) {
  x = fminf(fmaxf(x, -30.f), 30.f);
  float e = __expf(-x);
  return __builtin_amdgcn_rcpf(1.f + e);
}
__device__ __forceinline__ float tanh_(float x) {
  float x2 = fminf(fmaxf(2.f*x, -60.f), 60.f);
  float e = __expf(x2);
  return (e - 1.f) * __builtin_amdgcn_rcpf(e + 1.f);
}

// ---------------- prep kernels ----------------

__global__ __launch_bounds__(256) void cvt_pad_k(const float* __restrict__ src,
    u16* __restrict__ dst, int drows, int srows, int skc, int dkc)
{
  int idx = blockIdx.x*256 + threadIdx.x;
  int total = drows*dkc;
  if (idx >= total) return;
  int r = idx / dkc, k = idx - r*dkc;
  float v = (r < srows && k < skc) ? src[(size_t)r*skc + k] : 0.f;
  dst[idx] = __builtin_bit_cast(u16, (_Float16)v);
}

__global__ __launch_bounds__(256) void pack_pairs_k(const float* __restrict__ U,
    u32* __restrict__ dst)
{
  int idx = blockIdx.x*256 + threadIdx.x;  // 512*256
  if (idx >= 512*256) return;
  int i = idx >> 8, p = idx & 255;
  f16x2 v;
  v[0] = (_Float16)U[(size_t)i*512 + 2*p];
  v[1] = (_Float16)U[(size_t)i*512 + 2*p + 1];
  dst[idx] = __builtin_bit_cast(u32, v);
}

__global__ __launch_bounds__(256) void cat3_k(const float* __restrict__ a,
    const float* __restrict__ b, const float* __restrict__ c, float* __restrict__ d)
{
  int i = blockIdx.x*256 + threadIdx.x;
  if (i < 512) d[i] = a[i];
  else if (i < 1024) d[i] = b[i-512];
  else if (i < 1536) d[i] = c[i-1024];
}

__global__ __launch_bounds__(256) void scan_init_k(u32* __restrict__ h_ex,
                                                   u32* __restrict__ g_ex)
{
  int i = blockIdx.x*256 + threadIdx.x;   // grid 128*256 = 32768
  if (i < 32768) { h_ex[i] = 0u; g_ex[i] = 0u; }  // tag0|payload0 = h(0)=0
}

// ---------------- GEMM (f16 MFMA, A:[M][K], B:[N][K] row-major = B^T) ----------

template<bool OUT_HALF, bool NGUARD>
__global__ __launch_bounds__(256) void gemm_f16_k(
    const u16* __restrict__ A, const u16* __restrict__ B,
    const float* __restrict__ bias, void* __restrict__ Cout,
    int K, int ntiles, int ldc, int nreal)
{
  __shared__ __align__(16) u16 As[128*40];   // row stride 40 f16 = 80B
  __shared__ __align__(16) u16 Bs[128*40];
  const int blk = blockIdx.x;
  const int bm = blk / ntiles, bn = blk % ntiles;
  const int t = threadIdx.x;
  const int l = t & 63, w = t >> 6;
  const int wr = w >> 1, wc = w & 1;
  const int srow = t >> 1, kh = t & 1;
  const int lr = l & 15, kb = l >> 4;

  f32x4 acc[4][4];
  #pragma unroll
  for (int m = 0; m < 4; ++m)
    #pragma unroll
    for (int n = 0; n < 4; ++n) acc[m][n] = (f32x4)0.0f;

  const u16* pa = A + (size_t)(bm*128 + srow)*K + kh*16;
  const u16* pb = B + (size_t)(bn*128 + srow)*K + kh*16;
  const int ktiles = K >> 5;
  for (int kt = 0; kt < ktiles; ++kt) {
    uint4 va0 = *(const uint4*)(pa);
    uint4 va1 = *(const uint4*)(pa + 8);
    uint4 vb0 = *(const uint4*)(pb);
    uint4 vb1 = *(const uint4*)(pb + 8);
    pa += 32; pb += 32;
    __syncthreads();
    *(uint4*)(As + srow*40 + kh*16)     = va0;
    *(uint4*)(As + srow*40 + kh*16 + 8) = va1;
    *(uint4*)(Bs + srow*40 + kh*16)     = vb0;
    *(uint4*)(Bs + srow*40 + kh*16 + 8) = vb1;
    __syncthreads();
    f16x8 af[4], bf[4];
    #pragma unroll
    for (int m = 0; m < 4; ++m)
      af[m] = *(const f16x8*)(As + (wr*64 + m*16 + lr)*40 + kb*8);
    #pragma unroll
    for (int n = 0; n < 4; ++n)
      bf[n] = *(const f16x8*)(Bs + (wc*64 + n*16 + lr)*40 + kb*8);
    #pragma unroll
    for (int m = 0; m < 4; ++m)
      #pragma unroll
      for (int n = 0; n < 4; ++n)
        acc[m][n] = __builtin_amdgcn_mfma_f32_16x16x32_f16(af[m], bf[n], acc[m][n], 0, 0, 0);
  }

  #pragma unroll
  for (int n = 0; n < 4; ++n) {
    int col = bn*128 + wc*64 + n*16 + lr;
    bool ok = (!NGUARD) || (col < nreal);
    float bv = ok ? bias[col] : 0.f;
    #pragma unroll
    for (int m = 0; m < 4; ++m) {
      #pragma unroll
      for (int r = 0; r < 4; ++r) {
        int row = bm*128 + wr*64 + m*16 + kb*4 + r;
        float v = acc[m][n][r] + bv;
        if (ok) {
          if (OUT_HALF)
            ((u16*)Cout)[(size_t)row*ldc + col] = __builtin_bit_cast(u16, (_Float16)v);
          else
            ((float*)Cout)[(size_t)row*ldc + col] = v;
        }
      }
    }
  }
}

// ---------------- GRU scan ----------------
// WG (pb, part): outputs [part*64, part*64+64) for BOTH chains (fwd, bwd).
// Thread: iout = t0>>3, jg = t0&7. Weights 96 u32 in VGPRs.
// Exchange word = (tag<<16)|f16. h(t) tag=t (slot t&1); g of step t tag=t+1
// (slot t&1). Poll: thread t0 handles chain pc=t0>>8, word-pair w2=t0&255.
// LDS stage slot(w2) = w2 + 4*(w2>>5)  (stride-36 per jg: b128 conflict-free).

#define POLL_PAIR(ptr, need, dst) do { u32 _n = 0; \
    for (;;) { \
      u64 _w = __hip_atomic_load((const u64*)(void*)(ptr), __ATOMIC_RELAXED, \
                                 __HIP_MEMORY_SCOPE_AGENT); \
      u32 _lo = (u32)_w, _hi = (u32)(_w >> 32); \
      if ((_lo >> 16) >= (u32)(need) && (_hi >> 16) >= (u32)(need)) { \
        (dst) = (_lo & 0xFFFFu) | (_hi << 16); break; } \
      if (dead) { (dst) = 0u; break; } \
      if (++_n > SPIN_CAP) { dead = 1; (dst) = 0u; break; } \
    } } while (0)

__global__ __launch_bounds__(512, 2) void gru_scan_k(
    const u16* __restrict__ xproj,   // [16000][1536] f16, gates z,r,h
    const u32* __restrict__ Upack,   // [3][512][256] f16x2 pairs (z,r,h)
    u16* __restrict__ outh,          // [16000][1024] f16
    u32* __restrict__ h_ex,          // [16 pb][2 chain][2 par][512] tagged
    u32* __restrict__ g_ex)          // same
{
  __shared__ __align__(16) u32 stageA[2][288];   // h pairs per chain
  __shared__ __align__(16) u32 stageB[2][288];   // g pairs per chain
  __shared__ volatile int dead;
  const int bid  = blockIdx.x;
  const int part = bid >> 4;         // bid = part*16 + pb
  const int pb   = bid & 15;
  const int t0   = threadIdx.x;
  const int iout = t0 >> 3;
  const int jg   = t0 & 7;
  const int ig   = part*64 + iout;
  const int pc   = t0 >> 8;          // poll chain (0/1)
  const int w2   = t0 & 255;         // poll word-pair
  const int slot = w2 + 4*(w2 >> 5);

  if (t0 == 0) dead = 0;

  u32 wz[32], wr_[32], wh[32];
  {
    const uint4* pz = (const uint4*)(Upack + ((size_t)(0*512 + ig)*256 + jg*32));
    const uint4* pr = (const uint4*)(Upack + ((size_t)(1*512 + ig)*256 + jg*32));
    const uint4* ph = (const uint4*)(Upack + ((size_t)(2*512 + ig)*256 + jg*32));
    #pragma unroll
    for (int k = 0; k < 8; ++k) {
      uint4 vz = pz[k]; wz[4*k]=vz.x;  wz[4*k+1]=vz.y;  wz[4*k+2]=vz.z;  wz[4*k+3]=vz.w;
      uint4 vr = pr[k]; wr_[4*k]=vr.x; wr_[4*k+1]=vr.y; wr_[4*k+2]=vr.z; wr_[4*k+3]=vr.w;
      uint4 vh = ph[k]; wh[4*k]=vh.x;  wh[4*k+1]=vh.y;  wh[4*k+2]=vh.z;  wh[4*k+3]=vh.w;
    }
  }
  __syncthreads();

  // per-(pb,chain) bases: [2 par][512] words
  u32* hex0 = h_ex + (pb*2 + 0)*1024;
  u32* hex1 = h_ex + (pb*2 + 1)*1024;
  u32* gex0 = g_ex + (pb*2 + 0)*1024;
  u32* gex1 = g_ex + (pb*2 + 1)*1024;
  u32* hpoll = (pc ? hex1 : hex0);   // this thread's poll target
  u32* gpoll = (pc ? gex1 : gex0);

  float hprev0 = 0.f, hprev1 = 0.f;

  for (int t = 0; t < T_STEPS; ++t) {
    const int par  = t & 1;
    const int row0 = t*NB + pb;
    const int row1 = (T_STEPS-1 - t)*NB + pb;

    // x-projection loads (h-independent, L2-cached) — issue before the poll
    const u16* xp0 = xproj + (size_t)row0*1536 + ig;
    const u16* xp1 = xproj + (size_t)row1*1536 + ig;
    float xz0 = (float)__builtin_bit_cast(_Float16, xp0[0]);
    float xr0 = (float)__builtin_bit_cast(_Float16, xp0[512]);
    float xh0 = (float)__builtin_bit_cast(_Float16, xp0[1024]);
    float xz1 = (float)__builtin_bit_cast(_Float16, xp1[0]);
    float xr1 = (float)__builtin_bit_cast(_Float16, xp1[512]);
    float xh1 = (float)__builtin_bit_cast(_Float16, xp1[1024]);

    // ---- stage h(t): poll tagged pair, deposit to LDS ----
    {
      u32 pair;
      POLL_PAIR(hpoll + par*512 + 2*w2, t, pair);
      stageA[pc][slot] = pair;
    }
    __syncthreads();

    // ---- phase A: z/r matvecs on h(t) ----
    float az0=0.f, ar0=0.f, az1=0.f, ar1=0.f;
    {
      const uint4* h0p = (const uint4*)(&stageA[0][jg*36]);
      const uint4* h1p = (const uint4*)(&stageA[1][jg*36]);
      #pragma unroll
      for (int k = 0; k < 8; ++k) {
        uint4 a = h0p[k], b = h1p[k];
        az0=fdot2f(wz[4*k+0],a.x,az0); ar0=fdot2f(wr_[4*k+0],a.x,ar0);
        az1=fdot2f(wz[4*k+0],b.x,az1); ar1=fdot2f(wr_[4*k+0],b.x,ar1);
        az0=fdot2f(wz[4*k+1],a.y,az0); ar0=fdot2f(wr_[4*k+1],a.y,ar0);
        az1=fdot2f(wz[4*k+1],b.y,az1); ar1=fdot2f(wr_[4*k+1],b.y,ar1);
        az0=fdot2f(wz[4*k+2],a.z,az0); ar0=fdot2f(wr_[4*k+2],a.z,ar0);
        az1=fdot2f(wz[4*k+2],b.z,az1); ar1=fdot2f(wr_[4*k+2],b.z,ar1);
        az0=fdot2f(wz[4*k+3],a.w,az0); ar0=fdot2f(wr_[4*k+3],a.w,ar0);
        az1=fdot2f(wz[4*k+3],b.w,az1); ar1=fdot2f(wr_[4*k+3],b.w,ar1);
      }
    }
    #pragma unroll
    for (int m = 1; m < 8; m <<= 1) {
      az0 += __shfl_xor(az0, m); ar0 += __shfl_xor(ar0, m);
      az1 += __shfl_xor(az1, m); ar1 += __shfl_xor(ar1, m);
    }
    float z0 = sigm_(xz0 + az0);
    float r0 = sigm_(xr0 + ar0);
    float g0 = r0 * hprev0;
    float z1 = sigm_(xz1 + az1);
    float r1 = sigm_(xr1 + ar1);
    float g1 = r1 * hprev1;

    // publish g (tag t+1) — single tagged words, no fences
    if (jg == 0) {
      u32 w0 = ((u32)(t+1) << 16) | (u32)__builtin_bit_cast(u16, (_Float16)g0);
      u32 w1 = ((u32)(t+1) << 16) | (u32)__builtin_bit_cast(u16, (_Float16)g1);
      __hip_atomic_store(gex0 + par*512 + ig, w0, __ATOMIC_RELAXED, __HIP_MEMORY_SCOPE_AGENT);
      __hip_atomic_store(gex1 + par*512 + ig, w1, __ATOMIC_RELAXED, __HIP_MEMORY_SCOPE_AGENT);
    }

    // ---- stage g (tag t+1) ----
    {
      u32 pair;
      POLL_PAIR(gpoll + par*512 + 2*w2, t+1, pair);
      stageB[pc][slot] = pair;
    }
    __syncthreads();

    // ---- phase B: Uh matvec on g, state update ----
    float ah0 = 0.f, ah1 = 0.f;
    {
      const uint4* g0p = (const uint4*)(&stageB[0][jg*36]);
      const uint4* g1p = (const uint4*)(&stageB[1][jg*36]);
      #pragma unroll
      for (int k = 0; k < 8; ++k) {
        uint4 a = g0p[k], b = g1p[k];
        ah0=fdot2f(wh[4*k+0],a.x,ah0); ah1=fdot2f(wh[4*k+0],b.x,ah1);
        ah0=fdot2f(wh[4*k+1],a.y,ah0); ah1=fdot2f(wh[4*k+1],b.y,ah1);
        ah0=fdot2f(wh[4*k+2],a.z,ah0); ah1=fdot2f(wh[4*k+2],b.z,ah1);
        ah0=fdot2f(wh[4*k+3],a.w,ah0); ah1=fdot2f(wh[4*k+3],b.w,ah1);
      }
    }
    #pragma unroll
    for (int m = 1; m < 8; m <<= 1) {
      ah0 += __shfl_xor(ah0, m); ah1 += __shfl_xor(ah1, m);
    }
    float c0  = tanh_(xh0 + ah0);
    float hn0 = z0*hprev0 + (1.f - z0)*c0;
    float c1  = tanh_(xh1 + ah1);
    float hn1 = z1*hprev1 + (1.f - z1)*c1;
    hprev0 = hn0; hprev1 = hn1;

    if (jg == 0) {
      u16 hb0 = __builtin_bit_cast(u16, (_Float16)hn0);
      u16 hb1 = __builtin_bit_cast(u16, (_Float16)hn1);
      u32 w0 = ((u32)(t+1) << 16) | (u32)hb0;
      u32 w1 = ((u32)(t+1) << 16) | (u32)hb1;
      __hip_atomic_store(hex0 + (par^1)*512 + ig, w0, __ATOMIC_RELAXED, __HIP_MEMORY_SCOPE_AGENT);
      __hip_atomic_store(hex1 + (par^1)*512 + ig, w1, __ATOMIC_RELAXED, __HIP_MEMORY_SCOPE_AGENT);
      outh[(size_t)row0*1024 + ig]       = hb0;  // fwd -> cols [0,512)
      outh[(size_t)row1*1024 + 512 + ig] = hb1;  // bwd -> cols [512,1024)
    }
  }
}

// ---------------- fused log_softmax + NLL + argmax-err (per row) ----------------

__global__ __launch_bounds__(256) void softmax_nll_k(float* __restrict__ dout,
    const int* __restrict__ lab, float2* __restrict__ part)
{
  __shared__ float sred[8];
  __shared__ int   sredi[4];
  const int row = blockIdx.x;
  float* p = dout + 2 + (size_t)row*NCLS;
  const int t = threadIdx.x;

  float v[8];
  float m = -1e30f; int mi = 0;
  #pragma unroll
  for (int j = 0; j < 8; ++j) {
    int c = t + 256*j;
    float x = (c < NCLS) ? p[c] : -1e30f;
    v[j] = x;
    if (x > m) { m = x; mi = c; }
  }
  #pragma unroll
  for (int off = 1; off < 64; off <<= 1) {
    float om = __shfl_xor(m, off); int oi = __shfl_xor(mi, off);
    if (om > m || (om == m && oi < mi)) { m = om; mi = oi; }
  }
  const int w = t >> 6;
  if ((t & 63) == 0) { sred[w] = m; sredi[w] = mi; }
  __syncthreads();
  if (t == 0) {
    #pragma unroll
    for (int k = 1; k < 4; ++k) {
      float om = sred[k]; int oi = sredi[k];
      if (om > m || (om == m && oi < mi)) { m = om; mi = oi; }
    }
    sred[4] = m; sredi[0] = mi;
  }
  __syncthreads();
  const float gmax = sred[4];
  const int   gidx = sredi[0];

  float s = 0.f;
  #pragma unroll
  for (int j = 0; j < 8; ++j) {
    int c = t + 256*j;
    if (c < NCLS) s += __expf(v[j] - gmax);
  }
  #pragma unroll
  for (int off = 1; off < 64; off <<= 1) s += __shfl_xor(s, off);
  if ((t & 63) == 0) sred[w] = s;
  __syncthreads();
  if (t == 0) sred[5] = gmax + __logf(sred[0] + sred[1] + sred[2] + sred[3]);
  __syncthreads();
  const float lse = sred[5];

  #pragma unroll
  for (int j = 0; j < 8; ++j) {
    int c = t + 256*j;
    if (c < NCLS) p[c] = v[j] - lse;
  }
  __syncthreads();
  if (t == 0) {
    int lb = lab[row];
    float nll = -p[lb];
    float ef = (gidx != lb) ? 1.f : 0.f;
    part[row] = make_float2(nll, ef);
  }
}

__global__ __launch_bounds__(1024) void finred_k(const float2* __restrict__ part,
                                                 float* __restrict__ out)
{
  __shared__ float s0[16], s1[16];
  float a = 0.f, e = 0.f;
  for (int i = threadIdx.x; i < ROWS; i += 1024) {
    float2 v = part[i]; a += v.x; e += v.y;
  }
  #pragma unroll
  for (int off = 1; off < 64; off <<= 1) { a += __shfl_xor(a, off); e += __shfl_xor(e, off); }
  if ((threadIdx.x & 63) == 0) { s0[threadIdx.x >> 6] = a; s1[threadIdx.x >> 6] = e; }
  __syncthreads();
  if (threadIdx.x == 0) {
    float ta = 0.f, te = 0.f;
    #pragma unroll
    for (int k = 0; k < 16; ++k) { ta += s0[k]; te += s1[k]; }
    out[0] = ta * (1.f/16000.f);
    out[1] = te * (1.f/16000.f);
  }
}

// ---------------- launch ----------------

extern "C" void kernel_launch(void* const* d_in, const int* in_sizes, int n_in,
                              void* d_out, int out_size, void* d_ws, size_t ws_size,
                              hipStream_t stream)
{
  const float* x     = (const float*)d_in[0];
  const int*   lab   = (const int*)  d_in[1];
  const float* w0_zx = (const float*)d_in[3];
  const float* b0_zx = (const float*)d_in[4];
  const float* w0_hx = (const float*)d_in[5];
  const float* b0_hx = (const float*)d_in[6];
  const float* w0_rx = (const float*)d_in[7];
  const float* b0_rx = (const float*)d_in[8];
  const float* u0_zh = (const float*)d_in[9];
  const float* u0_hh = (const float*)d_in[10];
  const float* u0_rh = (const float*)d_in[11];
  const float* w1_zx = (const float*)d_in[12];
  const float* b1_zx = (const float*)d_in[13];
  const float* w1_hx = (const float*)d_in[14];
  const float* b1_hx = (const float*)d_in[15];
  const float* w1_rx = (const float*)d_in[16];
  const float* b1_rx = (const float*)d_in[17];
  const float* u1_zh = (const float*)d_in[18];
  const float* u1_hh = (const float*)d_in[19];
  const float* u1_rh = (const float*)d_in[20];
  const float* fco_w = (const float*)d_in[21];
  const float* fco_b = (const float*)d_in[22];

  char* ws = (char*)d_ws;
  u16*   xf    = (u16*)  (ws + 0);            // [16000][448] f16
  u16*   w0c   = (u16*)  (ws + 14336000);     // [1536][448]
  float* b0c   = (float*)(ws + 15712256);     // [1536]
  u32*   u0p   = (u32*)  (ws + 15718400);     // [3][512][256]
  u16*   w1c   = (u16*)  (ws + 17291264);     // [1536][1024]
  float* b1c   = (float*)(ws + 20436992);
  u32*   u1p   = (u32*)  (ws + 20443136);
  u16*   fcoc  = (u16*)  (ws + 22016000);     // [2048][1024]
  u16*   x1    = (u16*)  (ws + 26210304);     // [16000][1024] f16
  float2* part = (float2*)(ws + 58978304);    // [16000]
  u32*   h_ex  = (u32*)  (ws + 59106304);     // [16][2][2][512] tagged u32
  u32*   g_ex  = (u32*)  (ws + 59237376);     // [16][2][2][512]
  float* out   = (float*)d_out;
  u16*   xproj = (u16*)  (out + 2);           // [16000][1536] f16 scratch in
                                              //  logits area (dead before
                                              //  classifier overwrites it)

  // prep: f32 -> f16 (+padding), gate order z,r,h; biases concatenated
  cvt_pad_k<<<28000,256,0,stream>>>(x, xf, ROWS, ROWS, DIN, DINP);
  cvt_pad_k<<<896,256,0,stream>>>(w0_zx, w0c,          512,512, DIN, DINP);
  cvt_pad_k<<<896,256,0,stream>>>(w0_rx, w0c+512*448,  512,512, DIN, DINP);
  cvt_pad_k<<<896,256,0,stream>>>(w0_hx, w0c+1024*448, 512,512, DIN, DINP);
  cat3_k<<<6,256,0,stream>>>(b0_zx, b0_rx, b0_hx, b0c);
  pack_pairs_k<<<512,256,0,stream>>>(u0_zh, u0p);
  pack_pairs_k<<<512,256,0,stream>>>(u0_rh, u0p + 131072);
  pack_pairs_k<<<512,256,0,stream>>>(u0_hh, u0p + 262144);
  cvt_pad_k<<<2048,256,0,stream>>>(w1_zx, w1c,            512,512, 1024,1024);
  cvt_pad_k<<<2048,256,0,stream>>>(w1_rx, w1c+512*1024,   512,512, 1024,1024);
  cvt_pad_k<<<2048,256,0,stream>>>(w1_hx, w1c+1024*1024,  512,512, 1024,1024);
  cat3_k<<<6,256,0,stream>>>(b1_zx, b1_rx, b1_hx, b1c);
  pack_pairs_k<<<512,256,0,stream>>>(u1_zh, u1p);
  pack_pairs_k<<<512,256,0,stream>>>(u1_rh, u1p + 131072);
  pack_pairs_k<<<512,256,0,stream>>>(u1_hh, u1p + 262144);
  cvt_pad_k<<<8192,256,0,stream>>>(fco_w, fcoc, NCLSP, NCLS, 1024, 1024);

  // pipeline
  gemm_f16_k<true,false><<<125*12,256,0,stream>>>(xf,  w0c, b0c, xproj, DINP, 12, 1536, 1536);
  scan_init_k<<<128,256,0,stream>>>(h_ex, g_ex);
  gru_scan_k<<<128,512,0,stream>>>(xproj, u0p, x1, h_ex, g_ex);
  gemm_f16_k<true,false><<<125*12,256,0,stream>>>(x1,  w1c, b1c, xproj, 1024, 12, 1536, 1536);
  scan_init_k<<<128,256,0,stream>>>(h_ex, g_ex);
  gru_scan_k<<<128,512,0,stream>>>(xproj, u1p, x1, h_ex, g_ex);
  gemm_f16_k<false,true><<<125*16,256,0,stream>>>(x1, fcoc, fco_b, out + 2, 1024, 16, NCLS, NCLS);

  softmax_nll_k<<<ROWS,256,0,stream>>>(out, lab, part);
  finred_k<<<1,1024,0,stream>>>(part, out);
}

// Round 8
// 7365.041 us; speedup vs baseline: 12.3145x; 1.2985x over previous
//
#include <hip/hip_runtime.h>

// GRU bidirectional 2-layer + classifier for MI355X (gfx950).
// Reference GRU variant: hcand = tanh(h_in + (r ⊙ h_prev) @ Uh^T).
// Scan: 128 WGs = 16 batch x 8 output-parts, weights in VGPRs.
// Fence-free tagged exchange ((tag<<16)|f16 words, relaxed agent atomics).
// r8: u64 combined-chain publish/poll, 2-deep pipelined spin sampling,
// dead-check off the hot path, publish-g before z on the critical path.

#define T_STEPS 1000
#define NB      16
#define DH      512
#define ROWS    (T_STEPS*NB)   // 16000
#define DIN     440
#define DINP    448
#define NCLS    2000
#define NCLSP   2048
#define SPIN_CAP 20000u

typedef _Float16 f16;
typedef _Float16 f16x2 __attribute__((ext_vector_type(2)));
typedef _Float16 f16x8 __attribute__((ext_vector_type(8)));
typedef float    f32x4 __attribute__((ext_vector_type(4)));
typedef unsigned int   u32;
typedef unsigned short u16;
typedef unsigned long long u64;

__device__ __forceinline__ float fdot2f(u32 a, u32 b, float c) {
#if __has_builtin(__builtin_amdgcn_fdot2)
  return __builtin_amdgcn_fdot2(__builtin_bit_cast(f16x2, a),
                                __builtin_bit_cast(f16x2, b), c, false);
#else
  f16x2 av = __builtin_bit_cast(f16x2, a), bv = __builtin_bit_cast(f16x2, b);
  return c + (float)av[0]*(float)bv[0] + (float)av[1]*(float)bv[1];
#endif
}

__device__ __forceinline__ float sigm_(float x) {
  x = fminf(fmaxf(x, -30.f), 30.f);
  float e = __expf(-x);
  return __builtin_amdgcn_rcpf(1.f + e);
}
__device__ __forceinline__ float tanh_(float x) {
  float x2 = fminf(fmaxf(2.f*x, -60.f), 60.f);
  float e = __expf(x2);
  return (e - 1.f) * __builtin_amdgcn_rcpf(e + 1.f);
}

// ---------------- prep kernels ----------------

__global__ __launch_bounds__(256) void cvt_pad_k(const float* __restrict__ src,
    u16* __restrict__ dst, int drows, int srows, int skc, int dkc)
{
  int idx = blockIdx.x*256 + threadIdx.x;
  int total = drows*dkc;
  if (idx >= total) return;
  int r = idx / dkc, k = idx - r*dkc;
  float v = (r < srows && k < skc) ? src[(size_t)r*skc + k] : 0.f;
  dst[idx] = __builtin_bit_cast(u16, (_Float16)v);
}

__global__ __launch_bounds__(256) void pack_pairs_k(const float* __restrict__ U,
    u32* __restrict__ dst)
{
  int idx = blockIdx.x*256 + threadIdx.x;  // 512*256
  if (idx >= 512*256) return;
  int i = idx >> 8, p = idx & 255;
  f16x2 v;
  v[0] = (_Float16)U[(size_t)i*512 + 2*p];
  v[1] = (_Float16)U[(size_t)i*512 + 2*p + 1];
  dst[idx] = __builtin_bit_cast(u32, v);
}

__global__ __launch_bounds__(256) void cat3_k(const float* __restrict__ a,
    const float* __restrict__ b, const float* __restrict__ c, float* __restrict__ d)
{
  int i = blockIdx.x*256 + threadIdx.x;
  if (i < 512) d[i] = a[i];
  else if (i < 1024) d[i] = b[i-512];
  else if (i < 1536) d[i] = c[i-1024];
}

__global__ __launch_bounds__(256) void scan_init_k(u64* __restrict__ h_ex,
                                                   u64* __restrict__ g_ex)
{
  int i = blockIdx.x*256 + threadIdx.x;   // grid 64*256 = 16384
  if (i < 16384) { h_ex[i] = 0ull; g_ex[i] = 0ull; }  // tag0|h(0)=0
}

// ---------------- GEMM (f16 MFMA, A:[M][K], B:[N][K] row-major = B^T) ----------

template<bool OUT_HALF, bool NGUARD>
__global__ __launch_bounds__(256) void gemm_f16_k(
    const u16* __restrict__ A, const u16* __restrict__ B,
    const float* __restrict__ bias, void* __restrict__ Cout,
    int K, int ntiles, int ldc, int nreal)
{
  __shared__ __align__(16) u16 As[128*40];   // row stride 40 f16 = 80B
  __shared__ __align__(16) u16 Bs[128*40];
  const int blk = blockIdx.x;
  const int bm = blk / ntiles, bn = blk % ntiles;
  const int t = threadIdx.x;
  const int l = t & 63, w = t >> 6;
  const int wr = w >> 1, wc = w & 1;
  const int srow = t >> 1, kh = t & 1;
  const int lr = l & 15, kb = l >> 4;

  f32x4 acc[4][4];
  #pragma unroll
  for (int m = 0; m < 4; ++m)
    #pragma unroll
    for (int n = 0; n < 4; ++n) acc[m][n] = (f32x4)0.0f;

  const u16* pa = A + (size_t)(bm*128 + srow)*K + kh*16;
  const u16* pb = B + (size_t)(bn*128 + srow)*K + kh*16;
  const int ktiles = K >> 5;
  for (int kt = 0; kt < ktiles; ++kt) {
    uint4 va0 = *(const uint4*)(pa);
    uint4 va1 = *(const uint4*)(pa + 8);
    uint4 vb0 = *(const uint4*)(pb);
    uint4 vb1 = *(const uint4*)(pb + 8);
    pa += 32; pb += 32;
    __syncthreads();
    *(uint4*)(As + srow*40 + kh*16)     = va0;
    *(uint4*)(As + srow*40 + kh*16 + 8) = va1;
    *(uint4*)(Bs + srow*40 + kh*16)     = vb0;
    *(uint4*)(Bs + srow*40 + kh*16 + 8) = vb1;
    __syncthreads();
    f16x8 af[4], bf[4];
    #pragma unroll
    for (int m = 0; m < 4; ++m)
      af[m] = *(const f16x8*)(As + (wr*64 + m*16 + lr)*40 + kb*8);
    #pragma unroll
    for (int n = 0; n < 4; ++n)
      bf[n] = *(const f16x8*)(Bs + (wc*64 + n*16 + lr)*40 + kb*8);
    #pragma unroll
    for (int m = 0; m < 4; ++m)
      #pragma unroll
      for (int n = 0; n < 4; ++n)
        acc[m][n] = __builtin_amdgcn_mfma_f32_16x16x32_f16(af[m], bf[n], acc[m][n], 0, 0, 0);
  }

  #pragma unroll
  for (int n = 0; n < 4; ++n) {
    int col = bn*128 + wc*64 + n*16 + lr;
    bool ok = (!NGUARD) || (col < nreal);
    float bv = ok ? bias[col] : 0.f;
    #pragma unroll
    for (int m = 0; m < 4; ++m) {
      #pragma unroll
      for (int r = 0; r < 4; ++r) {
        int row = bm*128 + wr*64 + m*16 + kb*4 + r;
        float v = acc[m][n][r] + bv;
        if (ok) {
          if (OUT_HALF)
            ((u16*)Cout)[(size_t)row*ldc + col] = __builtin_bit_cast(u16, (_Float16)v);
          else
            ((float*)Cout)[(size_t)row*ldc + col] = v;
        }
      }
    }
  }
}

// ---------------- GRU scan ----------------
// WG (pb, part): outputs [part*64, part*64+64) for BOTH chains (fwd, bwd).
// Thread: iout = t0>>3, jg = t0&7. Weights 96 u32 in VGPRs.
// Exchange: u64 per ig = {ch1 word, ch0 word}, word = (tag<<16)|f16.
// h(t): tag t, slot t&1. g of step t: tag t+1, slot t&1. Poller: thread t0
// polls ig=t0 (2-deep pipelined sampling), stages u16s to LDS (72-u16 jg
// stride -> conflict-free b128 reads), one barrier, compute.

#define POLL64(ptr, need, dlo, dhi) do { u32 _n = 0; \
    for (;;) { \
      u64 _a = __hip_atomic_load((const u64*)(void*)(ptr), __ATOMIC_RELAXED, \
                                 __HIP_MEMORY_SCOPE_AGENT); \
      u64 _b = __hip_atomic_load((const u64*)(void*)(ptr), __ATOMIC_RELAXED, \
                                 __HIP_MEMORY_SCOPE_AGENT); \
      u32 _l = (u32)_a, _h = (u32)(_a >> 32); \
      if ((_l >> 16) >= (u32)(need) && (_h >> 16) >= (u32)(need)) { \
        (dlo) = _l & 0xFFFFu; (dhi) = _h & 0xFFFFu; break; } \
      _l = (u32)_b; _h = (u32)(_b >> 32); \
      if ((_l >> 16) >= (u32)(need) && (_h >> 16) >= (u32)(need)) { \
        (dlo) = _l & 0xFFFFu; (dhi) = _h & 0xFFFFu; break; } \
      if ((_n & 31u) == 31u && dead) { (dlo) = 0u; (dhi) = 0u; break; } \
      if (++_n > SPIN_CAP) { dead = 1; (dlo) = 0u; (dhi) = 0u; break; } \
    } } while (0)

__global__ __launch_bounds__(512, 2) void gru_scan_k(
    const u16* __restrict__ xproj,   // [16000][1536] f16, gates z,r,h
    const u32* __restrict__ Upack,   // [3][512][256] f16x2 pairs (z,r,h)
    u16* __restrict__ outh,          // [16000][1024] f16
    u64* __restrict__ h_ex,          // [16 pb][2 par][512 ig] (ch1,ch0)
    u64* __restrict__ g_ex)          // same
{
  __shared__ __align__(16) u16 stA[2][576];   // h staging [chain][8 jg x 72]
  __shared__ __align__(16) u16 stB[2][576];   // g staging
  __shared__ volatile int dead;
  const int bid  = blockIdx.x;
  const int part = bid >> 4;         // bid = part*16 + pb -> parts share XCD
  const int pb   = bid & 15;
  const int t0   = threadIdx.x;
  const int iout = t0 >> 3;
  const int jg   = t0 & 7;
  const int ig   = part*64 + iout;
  const int slot = (t0 >> 6)*72 + (t0 & 63);   // staging slot for polled ig=t0

  if (t0 == 0) dead = 0;

  u32 wz[32], wr_[32], wh[32];
  {
    const uint4* pz = (const uint4*)(Upack + ((size_t)(0*512 + ig)*256 + jg*32));
    const uint4* pr = (const uint4*)(Upack + ((size_t)(1*512 + ig)*256 + jg*32));
    const uint4* ph = (const uint4*)(Upack + ((size_t)(2*512 + ig)*256 + jg*32));
    #pragma unroll
    for (int k = 0; k < 8; ++k) {
      uint4 vz = pz[k]; wz[4*k]=vz.x;  wz[4*k+1]=vz.y;  wz[4*k+2]=vz.z;  wz[4*k+3]=vz.w;
      uint4 vr = pr[k]; wr_[4*k]=vr.x; wr_[4*k+1]=vr.y; wr_[4*k+2]=vr.z; wr_[4*k+3]=vr.w;
      uint4 vh = ph[k]; wh[4*k]=vh.x;  wh[4*k+1]=vh.y;  wh[4*k+2]=vh.z;  wh[4*k+3]=vh.w;
    }
  }
  __syncthreads();

  u64* hexb = h_ex + pb*1024;   // [2 par][512]
  u64* gexb = g_ex + pb*1024;

  float hprev0 = 0.f, hprev1 = 0.f;

  for (int t = 0; t < T_STEPS; ++t) {
    const int par  = t & 1;
    const int row0 = t*NB + pb;
    const int row1 = (T_STEPS-1 - t)*NB + pb;

    // x-projection loads (h-independent, cached) — issue before the poll
    const u16* xp0 = xproj + (size_t)row0*1536 + ig;
    const u16* xp1 = xproj + (size_t)row1*1536 + ig;
    float xz0 = (float)__builtin_bit_cast(_Float16, xp0[0]);
    float xr0 = (float)__builtin_bit_cast(_Float16, xp0[512]);
    float xh0 = (float)__builtin_bit_cast(_Float16, xp0[1024]);
    float xz1 = (float)__builtin_bit_cast(_Float16, xp1[0]);
    float xr1 = (float)__builtin_bit_cast(_Float16, xp1[512]);
    float xh1 = (float)__builtin_bit_cast(_Float16, xp1[1024]);

    // ---- stage h(t): poll u64 (both chains), deposit u16s ----
    {
      u32 lo, hi;
      POLL64(hexb + par*512 + t0, t, lo, hi);
      stA[0][slot] = (u16)lo;
      stA[1][slot] = (u16)hi;
    }
    __syncthreads();

    // ---- phase A: z/r matvecs on h(t) ----
    float az0=0.f, ar0=0.f, az1=0.f, ar1=0.f;
    {
      const uint4* h0p = (const uint4*)(&stA[0][jg*72]);
      const uint4* h1p = (const uint4*)(&stA[1][jg*72]);
      #pragma unroll
      for (int k = 0; k < 8; ++k) {
        uint4 a = h0p[k], b = h1p[k];
        az0=fdot2f(wz[4*k+0],a.x,az0); ar0=fdot2f(wr_[4*k+0],a.x,ar0);
        az1=fdot2f(wz[4*k+0],b.x,az1); ar1=fdot2f(wr_[4*k+0],b.x,ar1);
        az0=fdot2f(wz[4*k+1],a.y,az0); ar0=fdot2f(wr_[4*k+1],a.y,ar0);
        az1=fdot2f(wz[4*k+1],b.y,az1); ar1=fdot2f(wr_[4*k+1],b.y,ar1);
        az0=fdot2f(wz[4*k+2],a.z,az0); ar0=fdot2f(wr_[4*k+2],a.z,ar0);
        az1=fdot2f(wz[4*k+2],b.z,az1); ar1=fdot2f(wr_[4*k+2],b.z,ar1);
        az0=fdot2f(wz[4*k+3],a.w,az0); ar0=fdot2f(wr_[4*k+3],a.w,ar0);
        az1=fdot2f(wz[4*k+3],b.w,az1); ar1=fdot2f(wr_[4*k+3],b.w,ar1);
      }
    }
    // reduce r first — publish g as early as possible, z can wait
    #pragma unroll
    for (int m = 1; m < 8; m <<= 1) { ar0 += __shfl_xor(ar0, m); ar1 += __shfl_xor(ar1, m); }
    float r0 = sigm_(xr0 + ar0);
    float r1 = sigm_(xr1 + ar1);
    float g0 = r0 * hprev0;
    float g1 = r1 * hprev1;
    if (jg == 0) {
      u32 w0 = ((u32)(t+1) << 16) | (u32)__builtin_bit_cast(u16, (_Float16)g0);
      u32 w1 = ((u32)(t+1) << 16) | (u32)__builtin_bit_cast(u16, (_Float16)g1);
      u64 wv = ((u64)w1 << 32) | (u64)w0;
      __hip_atomic_store(gexb + par*512 + ig, wv, __ATOMIC_RELAXED, __HIP_MEMORY_SCOPE_AGENT);
    }
    #pragma unroll
    for (int m = 1; m < 8; m <<= 1) { az0 += __shfl_xor(az0, m); az1 += __shfl_xor(az1, m); }
    float z0 = sigm_(xz0 + az0);
    float z1 = sigm_(xz1 + az1);

    // ---- stage g (tag t+1) ----
    {
      u32 lo, hi;
      POLL64(gexb + par*512 + t0, t+1, lo, hi);
      stB[0][slot] = (u16)lo;
      stB[1][slot] = (u16)hi;
    }
    __syncthreads();

    // ---- phase B: Uh matvec on g, state update ----
    float ah0 = 0.f, ah1 = 0.f;
    {
      const uint4* g0p = (const uint4*)(&stB[0][jg*72]);
      const uint4* g1p = (const uint4*)(&stB[1][jg*72]);
      #pragma unroll
      for (int k = 0; k < 8; ++k) {
        uint4 a = g0p[k], b = g1p[k];
        ah0=fdot2f(wh[4*k+0],a.x,ah0); ah1=fdot2f(wh[4*k+0],b.x,ah1);
        ah0=fdot2f(wh[4*k+1],a.y,ah0); ah1=fdot2f(wh[4*k+1],b.y,ah1);
        ah0=fdot2f(wh[4*k+2],a.z,ah0); ah1=fdot2f(wh[4*k+2],b.z,ah1);
        ah0=fdot2f(wh[4*k+3],a.w,ah0); ah1=fdot2f(wh[4*k+3],b.w,ah1);
      }
    }
    #pragma unroll
    for (int m = 1; m < 8; m <<= 1) { ah0 += __shfl_xor(ah0, m); ah1 += __shfl_xor(ah1, m); }
    float c0  = tanh_(xh0 + ah0);
    float hn0 = z0*hprev0 + (1.f - z0)*c0;
    float c1  = tanh_(xh1 + ah1);
    float hn1 = z1*hprev1 + (1.f - z1)*c1;
    hprev0 = hn0; hprev1 = hn1;

    u16 hb0 = __builtin_bit_cast(u16, (_Float16)hn0);
    u16 hb1 = __builtin_bit_cast(u16, (_Float16)hn1);
    if (jg == 0) {
      u32 w0 = ((u32)(t+1) << 16) | (u32)hb0;
      u32 w1 = ((u32)(t+1) << 16) | (u32)hb1;
      u64 wv = ((u64)w1 << 32) | (u64)w0;
      __hip_atomic_store(hexb + (par^1)*512 + ig, wv, __ATOMIC_RELAXED, __HIP_MEMORY_SCOPE_AGENT);
      outh[(size_t)row0*1024 + ig]       = hb0;  // fwd -> cols [0,512)
      outh[(size_t)row1*1024 + 512 + ig] = hb1;  // bwd -> cols [512,1024)
    }
  }
}

// ---------------- fused log_softmax + NLL + argmax-err (per row) ----------------

__global__ __launch_bounds__(256) void softmax_nll_k(float* __restrict__ dout,
    const int* __restrict__ lab, float2* __restrict__ part)
{
  __shared__ float sred[8];
  __shared__ int   sredi[4];
  const int row = blockIdx.x;
  float* p = dout + 2 + (size_t)row*NCLS;
  const int t = threadIdx.x;

  float v[8];
  float m = -1e30f; int mi = 0;
  #pragma unroll
  for (int j = 0; j < 8; ++j) {
    int c = t + 256*j;
    float x = (c < NCLS) ? p[c] : -1e30f;
    v[j] = x;
    if (x > m) { m = x; mi = c; }
  }
  #pragma unroll
  for (int off = 1; off < 64; off <<= 1) {
    float om = __shfl_xor(m, off); int oi = __shfl_xor(mi, off);
    if (om > m || (om == m && oi < mi)) { m = om; mi = oi; }
  }
  const int w = t >> 6;
  if ((t & 63) == 0) { sred[w] = m; sredi[w] = mi; }
  __syncthreads();
  if (t == 0) {
    #pragma unroll
    for (int k = 1; k < 4; ++k) {
      float om = sred[k]; int oi = sredi[k];
      if (om > m || (om == m && oi < mi)) { m = om; mi = oi; }
    }
    sred[4] = m; sredi[0] = mi;
  }
  __syncthreads();
  const float gmax = sred[4];
  const int   gidx = sredi[0];

  float s = 0.f;
  #pragma unroll
  for (int j = 0; j < 8; ++j) {
    int c = t + 256*j;
    if (c < NCLS) s += __expf(v[j] - gmax);
  }
  #pragma unroll
  for (int off = 1; off < 64; off <<= 1) s += __shfl_xor(s, off);
  if ((t & 63) == 0) sred[w] = s;
  __syncthreads();
  if (t == 0) sred[5] = gmax + __logf(sred[0] + sred[1] + sred[2] + sred[3]);
  __syncthreads();
  const float lse = sred[5];

  #pragma unroll
  for (int j = 0; j < 8; ++j) {
    int c = t + 256*j;
    if (c < NCLS) p[c] = v[j] - lse;
  }
  __syncthreads();
  if (t == 0) {
    int lb = lab[row];
    float nll = -p[lb];
    float ef = (gidx != lb) ? 1.f : 0.f;
    part[row] = make_float2(nll, ef);
  }
}

__global__ __launch_bounds__(1024) void finred_k(const float2* __restrict__ part,
                                                 float* __restrict__ out)
{
  __shared__ float s0[16], s1[16];
  float a = 0.f, e = 0.f;
  for (int i = threadIdx.x; i < ROWS; i += 1024) {
    float2 v = part[i]; a += v.x; e += v.y;
  }
  #pragma unroll
  for (int off = 1; off < 64; off <<= 1) { a += __shfl_xor(a, off); e += __shfl_xor(e, off); }
  if ((threadIdx.x & 63) == 0) { s0[threadIdx.x >> 6] = a; s1[threadIdx.x >> 6] = e; }
  __syncthreads();
  if (threadIdx.x == 0) {
    float ta = 0.f, te = 0.f;
    #pragma unroll
    for (int k = 0; k < 16; ++k) { ta += s0[k]; te += s1[k]; }
    out[0] = ta * (1.f/16000.f);
    out[1] = te * (1.f/16000.f);
  }
}

// ---------------- launch ----------------

extern "C" void kernel_launch(void* const* d_in, const int* in_sizes, int n_in,
                              void* d_out, int out_size, void* d_ws, size_t ws_size,
                              hipStream_t stream)
{
  const float* x     = (const float*)d_in[0];
  const int*   lab   = (const int*)  d_in[1];
  const float* w0_zx = (const float*)d_in[3];
  const float* b0_zx = (const float*)d_in[4];
  const float* w0_hx = (const float*)d_in[5];
  const float* b0_hx = (const float*)d_in[6];
  const float* w0_rx = (const float*)d_in[7];
  const float* b0_rx = (const float*)d_in[8];
  const float* u0_zh = (const float*)d_in[9];
  const float* u0_hh = (const float*)d_in[10];
  const float* u0_rh = (const float*)d_in[11];
  const float* w1_zx = (const float*)d_in[12];
  const float* b1_zx = (const float*)d_in[13];
  const float* w1_hx = (const float*)d_in[14];
  const float* b1_hx = (const float*)d_in[15];
  const float* w1_rx = (const float*)d_in[16];
  const float* b1_rx = (const float*)d_in[17];
  const float* u1_zh = (const float*)d_in[18];
  const float* u1_hh = (const float*)d_in[19];
  const float* u1_rh = (const float*)d_in[20];
  const float* fco_w = (const float*)d_in[21];
  const float* fco_b = (const float*)d_in[22];

  char* ws = (char*)d_ws;
  u16*   xf    = (u16*)  (ws + 0);            // [16000][448] f16
  u16*   w0c   = (u16*)  (ws + 14336000);     // [1536][448]
  float* b0c   = (float*)(ws + 15712256);     // [1536]
  u32*   u0p   = (u32*)  (ws + 15718400);     // [3][512][256]
  u16*   w1c   = (u16*)  (ws + 17291264);     // [1536][1024]
  float* b1c   = (float*)(ws + 20436992);
  u32*   u1p   = (u32*)  (ws + 20443136);
  u16*   fcoc  = (u16*)  (ws + 22016000);     // [2048][1024]
  u16*   x1    = (u16*)  (ws + 26210304);     // [16000][1024] f16
  float2* part = (float2*)(ws + 58978304);    // [16000]
  u64*   h_ex  = (u64*)  (ws + 59106304);     // [16][2][512] u64
  u64*   g_ex  = (u64*)  (ws + 59237376);     // [16][2][512] u64
  float* out   = (float*)d_out;
  u16*   xproj = (u16*)  (out + 2);           // [16000][1536] f16 scratch in
                                              //  logits area (dead before
                                              //  classifier overwrites it)

  // prep: f32 -> f16 (+padding), gate order z,r,h; biases concatenated
  cvt_pad_k<<<28000,256,0,stream>>>(x, xf, ROWS, ROWS, DIN, DINP);
  cvt_pad_k<<<896,256,0,stream>>>(w0_zx, w0c,          512,512, DIN, DINP);
  cvt_pad_k<<<896,256,0,stream>>>(w0_rx, w0c+512*448,  512,512, DIN, DINP);
  cvt_pad_k<<<896,256,0,stream>>>(w0_hx, w0c+1024*448, 512,512, DIN, DINP);
  cat3_k<<<6,256,0,stream>>>(b0_zx, b0_rx, b0_hx, b0c);
  pack_pairs_k<<<512,256,0,stream>>>(u0_zh, u0p);
  pack_pairs_k<<<512,256,0,stream>>>(u0_rh, u0p + 131072);
  pack_pairs_k<<<512,256,0,stream>>>(u0_hh, u0p + 262144);
  cvt_pad_k<<<2048,256,0,stream>>>(w1_zx, w1c,            512,512, 1024,1024);
  cvt_pad_k<<<2048,256,0,stream>>>(w1_rx, w1c+512*1024,   512,512, 1024,1024);
  cvt_pad_k<<<2048,256,0,stream>>>(w1_hx, w1c+1024*1024,  512,512, 1024,1024);
  cat3_k<<<6,256,0,stream>>>(b1_zx, b1_rx, b1_hx, b1c);
  pack_pairs_k<<<512,256,0,stream>>>(u1_zh, u1p);
  pack_pairs_k<<<512,256,0,stream>>>(u1_rh, u1p + 131072);
  pack_pairs_k<<<512,256,0,stream>>>(u1_hh, u1p + 262144);
  cvt_pad_k<<<8192,256,0,stream>>>(fco_w, fcoc, NCLSP, NCLS, 1024, 1024);

  // pipeline
  gemm_f16_k<true,false><<<125*12,256,0,stream>>>(xf,  w0c, b0c, xproj, DINP, 12, 1536, 1536);
  scan_init_k<<<64,256,0,stream>>>(h_ex, g_ex);
  gru_scan_k<<<128,512,0,stream>>>(xproj, u0p, x1, h_ex, g_ex);
  gemm_f16_k<true,false><<<125*12,256,0,stream>>>(x1,  w1c, b1c, xproj, 1024, 12, 1536, 1536);
  scan_init_k<<<64,256,0,stream>>>(h_ex, g_ex);
  gru_scan_k<<<128,512,0,stream>>>(xproj, u1p, x1, h_ex, g_ex);
  gemm_f16_k<false,true><<<125*16,256,0,stream>>>(x1, fcoc, fco_b, out + 2, 1024, 16, NCLS, NCLS);

  softmax_nll_k<<<ROWS,256,0,stream>>>(out, lab, part);
  finred_k<<<1,1024,0,stream>>>(part, out);
}